// Round 4
// baseline (490.802 us; speedup 1.0000x reference)
//
#include <hip/hip_runtime.h>
#include <cstdint>

// ---------------------------------------------------------------------------
// JanusCrossAttention: B=2,S=2048, Q_DIM=KV_DIM=2048, H=16, D=128, KVH=4
// I/O fp32; internals bf16 MFMA, fp32 accumulate.
//   1. cvt q_stream -> bf16 sb ; transpose weights -> bf16 [N][K]
//   2. xq = sb @ wqT  (m97-style global_load_lds GEMM)
//   3. cvt kv_stream -> sb ; xkv = sb @ wkvT  (fused K|V, N=1024)
//   4. per-head RMSNorm xq, xk
//   5. V -> V^T layout [b][kvh][d][s]
//   6. flash attention, S^T-operand scheme (no P LDS round-trip) -> ao(=sb)
//   7. out = ao @ woT (fp32 out)
// ---------------------------------------------------------------------------

using bf16 = __bf16;
using bf16x4 = __attribute__((ext_vector_type(4))) __bf16;
using bf16x8 = __attribute__((ext_vector_type(8))) __bf16;
using s16x4  = __attribute__((ext_vector_type(4))) short;
using f32x4  = __attribute__((ext_vector_type(4))) float;

#define SEQ 2048
#define NH 16
#define NKVH 4
#define HD 128

// 16x16x16 bf16 MFMA (K=16) — C layout of a prior 16x16 MFMA feeds B directly.
#if defined(__has_builtin)
#if __has_builtin(__builtin_amdgcn_mfma_f32_16x16x16bf16_1k)
#define HAVE_1K 1
#endif
#endif
__device__ __forceinline__ f32x4 mfma_16x16x16(bf16x4 a, bf16x4 b, f32x4 c) {
#ifdef HAVE_1K
    return __builtin_amdgcn_mfma_f32_16x16x16bf16_1k(
        __builtin_bit_cast(s16x4, a), __builtin_bit_cast(s16x4, b), c, 0, 0, 0);
#else
    f32x4 d;
    asm volatile("v_mfma_f32_16x16x16_bf16 %0, %1, %2, %3"
                 : "=v"(d) : "v"(a), "v"(b), "v"(c));
    return d;
#endif
}

// async global->LDS, 16B per lane. LDS dest must be wave-uniform base + lane*16.
__device__ __forceinline__ void load_lds16(const bf16* g, bf16* l) {
    __builtin_amdgcn_global_load_lds(
        (const __attribute__((address_space(1))) unsigned int*)g,
        (__attribute__((address_space(3))) unsigned int*)l, 16, 0, 0);
}

// ---------------------------------------------------------------------------
__global__ __launch_bounds__(256) void cvt_f32_bf16(const float* __restrict__ in,
                                                    bf16* __restrict__ out, int n8) {
    int i = blockIdx.x * 256 + threadIdx.x;
    if (i >= n8) return;
    const float4* p = (const float4*)in + (long)i * 2;
    float4 f0 = p[0], f1 = p[1];
    bf16x8 o = {(bf16)f0.x, (bf16)f0.y, (bf16)f0.z, (bf16)f0.w,
                (bf16)f1.x, (bf16)f1.y, (bf16)f1.z, (bf16)f1.w};
    *((bf16x8*)out + i) = o;
}

// 2D transpose + cast: in fp32 [R][C] -> out bf16 [C][R]
__global__ void transpose2d(const float* __restrict__ in, bf16* __restrict__ out,
                            int R, int C) {
    __shared__ bf16 tile[32][33];
    int x  = blockIdx.x * 32 + threadIdx.x;
    int y0 = blockIdx.y * 32 + threadIdx.y;
#pragma unroll
    for (int i = 0; i < 32; i += 8) {
        int y = y0 + i;
        if (y < R && x < C) tile[threadIdx.y + i][threadIdx.x] = (bf16)in[(long)y * C + x];
    }
    __syncthreads();
    int ox  = blockIdx.y * 32 + threadIdx.x;
    int oy0 = blockIdx.x * 32 + threadIdx.y;
#pragma unroll
    for (int i = 0; i < 32; i += 8) {
        int oy = oy0 + i;
        if (oy < C && ox < R) out[(long)oy * R + ox] = tile[threadIdx.x][threadIdx.y + i];
    }
}

// xv part of xkv [b][s][512 + kvh*128 + d] (row stride given) -> vt [b][kvh][d][s]
__global__ void transpose_v(const bf16* __restrict__ xv, bf16* __restrict__ vt,
                            int stride) {
    __shared__ bf16 tile[32][33];
    int z = blockIdx.z; int b = z >> 2, kvh = z & 3;
    int d0 = blockIdx.x * 32, s0 = blockIdx.y * 32;
    const bf16* src = xv + (long)b * SEQ * stride + kvh * HD;
    int d = d0 + threadIdx.x;
#pragma unroll
    for (int i = 0; i < 32; i += 8) {
        int s = s0 + threadIdx.y + i;
        tile[threadIdx.y + i][threadIdx.x] = src[(long)s * stride + d];
    }
    __syncthreads();
    bf16* dst = vt + (long)(b * NKVH + kvh) * HD * SEQ;
    int s = s0 + threadIdx.x;
#pragma unroll
    for (int i = 0; i < 32; i += 8) {
        int dd = d0 + threadIdx.y + i;
        dst[(long)dd * SEQ + s] = tile[threadIdx.x][threadIdx.y + i];
    }
}

// ---------------------------------------------------------------------------
// GEMM: C[M][N] = A[M][K] @ BT[N][K]^T, bf16 in, fp32 acc, CT out.
// m97 recipe: 128x128 tile, BK=32, global_load_lds width-16 staging.
template <typename CT>
__global__ __launch_bounds__(256) void gemm_bt(const bf16* __restrict__ A,
                                               const bf16* __restrict__ BT,
                                               CT* __restrict__ C,
                                               int M, int N, int K) {
    __shared__ bf16 As[128][32];
    __shared__ bf16 Bs[128][32];
    const int tid  = threadIdx.x;
    const int wave = tid >> 6, lane = tid & 63;
    const int m0 = blockIdx.y * 128, n0 = blockIdx.x * 128;
    const int wm = (wave >> 1) * 64, wn = (wave & 1) * 64;
    const int lrow = lane & 15, quad = lane >> 4;
    const int lko = quad * 8;

    const bf16* ga0 = A  + (long)(m0 + (tid >> 2)) * K + (tid & 3) * 8;
    const bf16* ga1 = ga0 + 64L * K;
    const bf16* gb0 = BT + (long)(n0 + (tid >> 2)) * K + (tid & 3) * 8;
    const bf16* gb1 = gb0 + 64L * K;
    bf16* la0 = &As[0][0] + tid * 8;
    bf16* la1 = la0 + 2048;
    bf16* lb0 = &Bs[0][0] + tid * 8;
    bf16* lb1 = lb0 + 2048;

    f32x4 acc[4][4] = {};

    for (int k0 = 0; k0 < K; k0 += 32) {
        load_lds16(ga0 + k0, la0);
        load_lds16(ga1 + k0, la1);
        load_lds16(gb0 + k0, lb0);
        load_lds16(gb1 + k0, lb1);
        __syncthreads();
        bf16x8 af[4], bfr[4];
#pragma unroll
        for (int i = 0; i < 4; ++i) af[i]  = *(const bf16x8*)(&As[wm + i * 16 + lrow][lko]);
#pragma unroll
        for (int j = 0; j < 4; ++j) bfr[j] = *(const bf16x8*)(&Bs[wn + j * 16 + lrow][lko]);
#pragma unroll
        for (int i = 0; i < 4; ++i)
#pragma unroll
            for (int j = 0; j < 4; ++j)
                acc[i][j] = __builtin_amdgcn_mfma_f32_16x16x32_bf16(af[i], bfr[j], acc[i][j], 0, 0, 0);
        __syncthreads();
    }
#pragma unroll
    for (int i = 0; i < 4; ++i) {
        int mrow0 = m0 + wm + i * 16 + quad * 4;
#pragma unroll
        for (int j = 0; j < 4; ++j) {
            int ncol = n0 + wn + j * 16 + lrow;
#pragma unroll
            for (int r = 0; r < 4; ++r)
                C[(long)(mrow0 + r) * N + ncol] = (CT)acc[i][j][r];
        }
    }
}

// ---------------------------------------------------------------------------
// Per-head RMSNorm, wave per 128-vector, in-place.
__global__ __launch_bounds__(256) void rmsnorm_head(bf16* __restrict__ X,
                                                    const float* __restrict__ W,
                                                    int nvec, int lhpr, int stride) {
    int v = blockIdx.x * 4 + (threadIdx.x >> 6);
    int lane = threadIdx.x & 63;
    if (v >= nvec) return;
    int row = v >> lhpr, head = v & ((1 << lhpr) - 1);
    bf16* x = X + (long)row * stride + head * HD;
    float fa = (float)x[lane * 2], fb = (float)x[lane * 2 + 1];
    float ss = fa * fa + fb * fb;
#pragma unroll
    for (int off = 1; off < 64; off <<= 1) ss += __shfl_xor(ss, off, 64);
    float r = rsqrtf(ss * (1.0f / 128.0f) + 1e-5f);
    x[lane * 2]     = (bf16)(fa * r * W[lane * 2]);
    x[lane * 2 + 1] = (bf16)(fb * r * W[lane * 2 + 1]);
}

// ---------------------------------------------------------------------------
// Flash attention, S^T-operand scheme. Grid: (S/64, H, B), block 256 = 4 waves.
// Wave owns 16 q rows (one per lane-column: q = lane&15).
// QK: S^T = K·Q^T via 16x16x32 (A=K frag, B=Q frag) -> C[key=quad*4+r][q=lane&15].
// That C layout IS the 16x16x16 B-operand layout, so PV consumes P from
// registers: out^T = V^T · P^T via 16x16x16 (A=V^T frag, B=P frag). No P LDS.
// Q: [b][s][h*128+d] stride 2048; K: xkv stride kstride; VT: [b][kvh][d][s].
__global__ __launch_bounds__(256, 4) void attn_kernel(const bf16* __restrict__ Q,
                                                      const bf16* __restrict__ Kn,
                                                      const bf16* __restrict__ VT,
                                                      bf16* __restrict__ O, int kstride) {
    __shared__ bf16 Ks[64][136];   // [key][d], +8 pad
    __shared__ bf16 Vs[128][72];   // [d][key], +8 pad
    const int tid = threadIdx.x, wave = tid >> 6, lane = tid & 63;
    const int qt = blockIdx.x;
    const int h = blockIdx.y, b = blockIdx.z;
    const int kvh = h >> 2;
    const int lrow = lane & 15, quad = lane >> 4;
    const float scale = 0.08838834764831845f;  // 1/sqrt(128)

    const bf16* kbase = Kn + (long)b * SEQ * kstride + kvh * HD;
    const bf16* vbase = VT + (long)(b * NKVH + kvh) * HD * SEQ;  // row stride SEQ

    const int q0 = qt * 64;
    const int nkb = qt + 1;
    const int myq = q0 + wave * 16 + lrow;   // this lane's q row

    // Q B-fragments straight from global: B[n=q=lane&15][k=d=quad*8+j]
    const bf16* qrow = Q + ((long)(b * SEQ + myq)) * (NH * HD) + h * HD;
    bf16x8 bq[4];
#pragma unroll
    for (int ks = 0; ks < 4; ++ks)
        bq[ks] = *(const bf16x8*)(qrow + ks * 32 + quad * 8);

    float m_i = -__builtin_inff(), l_i = 0.f;
    f32x4 oT[8] = {};   // out^T: d = dt*16 + quad*4 + r, q = lane&15

    for (int kb = 0; kb < nkb; ++kb) {
        // stage K (64x128) and V^T (128x64)
#pragma unroll
        for (int p = 0; p < 4; ++p) {
            int c = p * 256 + tid;
            int r = c >> 4, dc = (c & 15) * 8;
            *(uint4*)(&Ks[r][dc]) = *(const uint4*)(kbase + (long)(kb * 64 + r) * kstride + dc);
        }
#pragma unroll
        for (int p = 0; p < 4; ++p) {
            int c = p * 256 + tid;
            int r = c >> 3, sc = (c & 7) * 8;
            *(uint4*)(&Vs[r][sc]) = *(const uint4*)(vbase + (long)r * SEQ + kb * 64 + sc);
        }
        __syncthreads();

        // S^T tiles: key-tile nt covers keys kb*64+nt*16+quad*4+{0..3} for q=lrow
        f32x4 st[4];
        const bool diag = (kb == nkb - 1);
#pragma unroll
        for (int nt = 0; nt < 4; ++nt) {
            f32x4 acc = {};
#pragma unroll
            for (int ks = 0; ks < 4; ++ks) {
                bf16x8 ak = *(const bf16x8*)(&Ks[nt * 16 + lrow][ks * 32 + quad * 8]);
                acc = __builtin_amdgcn_mfma_f32_16x16x32_bf16(ak, bq[ks], acc, 0, 0, 0);
            }
            if (diag) {
                int kp0 = kb * 64 + nt * 16 + quad * 4;
#pragma unroll
                for (int r = 0; r < 4; ++r)
                    st[nt][r] = (kp0 + r <= myq) ? acc[r] * scale : -__builtin_inff();
            } else {
#pragma unroll
                for (int r = 0; r < 4; ++r) st[nt][r] = acc[r] * scale;
            }
        }

        // per-lane online softmax (lane owns one q row; keys spread over quads)
        float mx = st[0][0];
#pragma unroll
        for (int nt = 0; nt < 4; ++nt)
#pragma unroll
            for (int r = 0; r < 4; ++r) mx = fmaxf(mx, st[nt][r]);
        mx = fmaxf(mx, __shfl_xor(mx, 16, 64));
        mx = fmaxf(mx, __shfl_xor(mx, 32, 64));
        float mnew = fmaxf(m_i, mx);
        float alpha = __expf(m_i - mnew);
        float rs = 0.f;
#pragma unroll
        for (int nt = 0; nt < 4; ++nt)
#pragma unroll
            for (int r = 0; r < 4; ++r) {
                float p = __expf(st[nt][r] - mnew);
                st[nt][r] = p;
                rs += p;
            }
        rs += __shfl_xor(rs, 16, 64);
        rs += __shfl_xor(rs, 32, 64);
        l_i = l_i * alpha + rs;
        m_i = mnew;
#pragma unroll
        for (int dt = 0; dt < 8; ++dt)
#pragma unroll
            for (int r = 0; r < 4; ++r) oT[dt][r] *= alpha;

        // P fragments (B-operand of 16x16x16): B[n=q=lane&15][k=key=quad*4+j]
        bf16x4 pf[4];
#pragma unroll
        for (int nt = 0; nt < 4; ++nt) {
            bf16x4 t = {(bf16)st[nt][0], (bf16)st[nt][1], (bf16)st[nt][2], (bf16)st[nt][3]};
            pf[nt] = t;
        }

        // PV: out^T += V^T · P^T, key-steps of 16
#pragma unroll
        for (int nt = 0; nt < 4; ++nt)
#pragma unroll
            for (int dt = 0; dt < 8; ++dt) {
                bf16x4 av = *(const bf16x4*)(&Vs[dt * 16 + lrow][nt * 16 + quad * 4]);
                oT[dt] = mfma_16x16x16(av, pf[nt], oT[dt]);
            }
        __syncthreads();  // protect Ks/Vs before next staging
    }

    // epilogue: lane writes q-row myq, d = dt*16+quad*4+{0..3} (8B stores)
    float inv_l = 1.0f / l_i;
    bf16* obase = O + ((long)(b * SEQ + myq)) * (NH * HD) + h * HD;
#pragma unroll
    for (int dt = 0; dt < 8; ++dt) {
        bf16x4 o = {(bf16)(oT[dt][0] * inv_l), (bf16)(oT[dt][1] * inv_l),
                    (bf16)(oT[dt][2] * inv_l), (bf16)(oT[dt][3] * inv_l)};
        *(bf16x4*)(obase + dt * 16 + quad * 4) = o;
    }
}

// ---------------------------------------------------------------------------
extern "C" void kernel_launch(void* const* d_in, const int* in_sizes, int n_in,
                              void* d_out, int out_size, void* d_ws, size_t ws_size,
                              hipStream_t stream) {
    const float* q_stream  = (const float*)d_in[0];
    const float* kv_stream = (const float*)d_in[1];
    const float* wq  = (const float*)d_in[2];
    const float* wk  = (const float*)d_in[3];
    const float* wv  = (const float*)d_in[4];
    const float* wo  = (const float*)d_in[5];
    const float* qnw = (const float*)d_in[6];
    const float* knw = (const float*)d_in[7];
    float* out = (float*)d_out;

    // workspace (bf16 elems), total 28M elems = 56MB
    bf16* ws   = (bf16*)d_ws;
    bf16* sb   = ws;                        // 8M: stream buf, later attn out
    bf16* wqT  = ws + 8L * 1024 * 1024;     // 4M: wq^T, later wo^T
    bf16* wkvT = wqT + 4L * 1024 * 1024;    // 2M: [wk^T ; wv^T] = [1024][2048]
    bf16* xq   = wkvT + 2L * 1024 * 1024;   // 8M: [4096][2048]
    bf16* xkv  = xq + 8L * 1024 * 1024;     // 4M: [4096][1024] = [K | V]
    bf16* vt   = xkv + 4L * 1024 * 1024;    // 2M: [b][kvh][d][s]

    dim3 tb(32, 8);
    cvt_f32_bf16<<<4096, 256, 0, stream>>>(q_stream, sb, 1048576);
    transpose2d<<<dim3(64, 64), tb, 0, stream>>>(wq, wqT, 2048, 2048);
    transpose2d<<<dim3(16, 64), tb, 0, stream>>>(wk, wkvT, 2048, 512);
    transpose2d<<<dim3(16, 64), tb, 0, stream>>>(wv, wkvT + 512L * 2048, 2048, 512);
    gemm_bt<bf16><<<dim3(16, 32), 256, 0, stream>>>(sb, wqT, xq, 4096, 2048, 2048);
    cvt_f32_bf16<<<4096, 256, 0, stream>>>(kv_stream, sb, 1048576);
    transpose2d<<<dim3(64, 64), tb, 0, stream>>>(wo, wqT, 2048, 2048);
    gemm_bt<bf16><<<dim3(8, 32), 256, 0, stream>>>(sb, wkvT, xkv, 4096, 1024, 2048);
    rmsnorm_head<<<(4096 * 16) / 4, 256, 0, stream>>>(xq, qnw, 4096 * 16, 4, 2048);
    rmsnorm_head<<<(4096 * 4) / 4, 256, 0, stream>>>(xkv, knw, 4096 * 4, 2, 1024);
    transpose_v<<<dim3(4, 64, 8), tb, 0, stream>>>(xkv + 512, vt, 1024);
    attn_kernel<<<dim3(32, 16, 2), 256, 0, stream>>>(xq, xkv, vt, sb, 1024);
    gemm_bt<float><<<dim3(16, 32), 256, 0, stream>>>(sb, wqT, out, 4096, 2048, 2048);

    (void)in_sizes; (void)n_in; (void)out_size; (void)ws_size;
}

// Round 5
// 417.822 us; speedup vs baseline: 1.1747x; 1.1747x over previous
//
#include <hip/hip_runtime.h>
#include <cstdint>

// ---------------------------------------------------------------------------
// JanusCrossAttention: B=2,S=2048, Q_DIM=KV_DIM=2048, H=16, D=128, KVH=4
// I/O fp32; internals bf16 MFMA, fp32 accumulate.
//   1. cvt q_stream -> bf16 sb ; transpose weights -> bf16 [N][K]
//   2. xq = sb @ wqT  (m97-style global_load_lds GEMM)
//   3. cvt kv_stream -> sb ; xkv = sb @ wkvT  (fused K|V, N=1024)
//   4. per-head RMSNorm xq, xk
//   5. repack K and V^T into MFMA-fragment-major tiles (conflict-free LDS)
//   6. flash attention: S^T register-P scheme + paired q-tiles + async staging
//   7. out = ao @ woT (fp32 out)
// ---------------------------------------------------------------------------

using bf16 = __bf16;
using bf16x4 = __attribute__((ext_vector_type(4))) __bf16;
using bf16x8 = __attribute__((ext_vector_type(8))) __bf16;
using s16x4  = __attribute__((ext_vector_type(4))) short;
using f32x4  = __attribute__((ext_vector_type(4))) float;

#define SEQ 2048
#define NH 16
#define NKVH 4
#define HD 128

// 16x16x16 bf16 MFMA (K=16) — C layout of a prior 16x16 MFMA feeds B directly.
#if defined(__has_builtin)
#if __has_builtin(__builtin_amdgcn_mfma_f32_16x16x16bf16_1k)
#define HAVE_1K 1
#endif
#endif
__device__ __forceinline__ f32x4 mfma_16x16x16(bf16x4 a, bf16x4 b, f32x4 c) {
#ifdef HAVE_1K
    return __builtin_amdgcn_mfma_f32_16x16x16bf16_1k(
        __builtin_bit_cast(s16x4, a), __builtin_bit_cast(s16x4, b), c, 0, 0, 0);
#else
    f32x4 d;
    asm volatile("v_mfma_f32_16x16x16_bf16 %0, %1, %2, %3"
                 : "=v"(d) : "v"(a), "v"(b), "v"(c));
    return d;
#endif
}

// async global->LDS, 16B per lane. LDS dest must be wave-uniform base + lane*16.
__device__ __forceinline__ void load_lds16(const bf16* g, bf16* l) {
    __builtin_amdgcn_global_load_lds(
        (const __attribute__((address_space(1))) unsigned int*)g,
        (__attribute__((address_space(3))) unsigned int*)l, 16, 0, 0);
}

// ---------------------------------------------------------------------------
__global__ __launch_bounds__(256) void cvt_f32_bf16(const float* __restrict__ in,
                                                    bf16* __restrict__ out, int n8) {
    int i = blockIdx.x * 256 + threadIdx.x;
    if (i >= n8) return;
    const float4* p = (const float4*)in + (long)i * 2;
    float4 f0 = p[0], f1 = p[1];
    bf16x8 o = {(bf16)f0.x, (bf16)f0.y, (bf16)f0.z, (bf16)f0.w,
                (bf16)f1.x, (bf16)f1.y, (bf16)f1.z, (bf16)f1.w};
    *((bf16x8*)out + i) = o;
}

// 2D transpose + cast: in fp32 [R][C] -> out bf16 [C][R]
__global__ void transpose2d(const float* __restrict__ in, bf16* __restrict__ out,
                            int R, int C) {
    __shared__ bf16 tile[32][33];
    int x  = blockIdx.x * 32 + threadIdx.x;
    int y0 = blockIdx.y * 32 + threadIdx.y;
#pragma unroll
    for (int i = 0; i < 32; i += 8) {
        int y = y0 + i;
        if (y < R && x < C) tile[threadIdx.y + i][threadIdx.x] = (bf16)in[(long)y * C + x];
    }
    __syncthreads();
    int ox  = blockIdx.y * 32 + threadIdx.x;
    int oy0 = blockIdx.x * 32 + threadIdx.y;
#pragma unroll
    for (int i = 0; i < 32; i += 8) {
        int oy = oy0 + i;
        if (oy < C && ox < R) out[(long)oy * R + ox] = tile[threadIdx.x][threadIdx.y + i];
    }
}

// ---------------------------------------------------------------------------
// GEMM: C[M][N] = A[M][K] @ BT[N][K]^T, bf16 in, fp32 acc, CT out.
// m97 recipe: 128x128 tile, BK=32, global_load_lds width-16 staging.
template <typename CT>
__global__ __launch_bounds__(256) void gemm_bt(const bf16* __restrict__ A,
                                               const bf16* __restrict__ BT,
                                               CT* __restrict__ C,
                                               int M, int N, int K) {
    __shared__ bf16 As[128][32];
    __shared__ bf16 Bs[128][32];
    const int tid  = threadIdx.x;
    const int wave = tid >> 6, lane = tid & 63;
    const int m0 = blockIdx.y * 128, n0 = blockIdx.x * 128;
    const int wm = (wave >> 1) * 64, wn = (wave & 1) * 64;
    const int lrow = lane & 15, quad = lane >> 4;
    const int lko = quad * 8;

    const bf16* ga0 = A  + (long)(m0 + (tid >> 2)) * K + (tid & 3) * 8;
    const bf16* ga1 = ga0 + 64L * K;
    const bf16* gb0 = BT + (long)(n0 + (tid >> 2)) * K + (tid & 3) * 8;
    const bf16* gb1 = gb0 + 64L * K;
    bf16* la0 = &As[0][0] + tid * 8;
    bf16* la1 = la0 + 2048;
    bf16* lb0 = &Bs[0][0] + tid * 8;
    bf16* lb1 = lb0 + 2048;

    f32x4 acc[4][4] = {};

    for (int k0 = 0; k0 < K; k0 += 32) {
        load_lds16(ga0 + k0, la0);
        load_lds16(ga1 + k0, la1);
        load_lds16(gb0 + k0, lb0);
        load_lds16(gb1 + k0, lb1);
        __syncthreads();
        bf16x8 af[4], bfr[4];
#pragma unroll
        for (int i = 0; i < 4; ++i) af[i]  = *(const bf16x8*)(&As[wm + i * 16 + lrow][lko]);
#pragma unroll
        for (int j = 0; j < 4; ++j) bfr[j] = *(const bf16x8*)(&Bs[wn + j * 16 + lrow][lko]);
#pragma unroll
        for (int i = 0; i < 4; ++i)
#pragma unroll
            for (int j = 0; j < 4; ++j)
                acc[i][j] = __builtin_amdgcn_mfma_f32_16x16x32_bf16(af[i], bfr[j], acc[i][j], 0, 0, 0);
        __syncthreads();
    }
#pragma unroll
    for (int i = 0; i < 4; ++i) {
        int mrow0 = m0 + wm + i * 16 + quad * 4;
#pragma unroll
        for (int j = 0; j < 4; ++j) {
            int ncol = n0 + wn + j * 16 + lrow;
#pragma unroll
            for (int r = 0; r < 4; ++r)
                C[(long)(mrow0 + r) * N + ncol] = (CT)acc[i][j][r];
        }
    }
}

// ---------------------------------------------------------------------------
// Per-head RMSNorm, wave per 128-vector, in-place.
__global__ __launch_bounds__(256) void rmsnorm_head(bf16* __restrict__ X,
                                                    const float* __restrict__ W,
                                                    int nvec, int lhpr, int stride) {
    int v = blockIdx.x * 4 + (threadIdx.x >> 6);
    int lane = threadIdx.x & 63;
    if (v >= nvec) return;
    int row = v >> lhpr, head = v & ((1 << lhpr) - 1);
    bf16* x = X + (long)row * stride + head * HD;
    float fa = (float)x[lane * 2], fb = (float)x[lane * 2 + 1];
    float ss = fa * fa + fb * fb;
#pragma unroll
    for (int off = 1; off < 64; off <<= 1) ss += __shfl_xor(ss, off, 64);
    float r = rsqrtf(ss * (1.0f / 128.0f) + 1e-5f);
    x[lane * 2]     = (bf16)(fa * r * W[lane * 2]);
    x[lane * 2 + 1] = (bf16)(fb * r * W[lane * 2 + 1]);
}

// ---------------------------------------------------------------------------
// Repack K (post-RMSNorm) into fragment-major tiles:
// kf[(b*4+kvh)*32 + kt][nt(4)][ks(4)][lane(64)][8] with
//   key = kt*64 + nt*16 + (lane&15), d = ks*32 + (lane>>4)*8 + j.
// This is exactly the 16x16x32 A-operand order -> attn LDS reads at lane*16.
__global__ __launch_bounds__(256) void repack_k(const bf16* __restrict__ xkv,
                                                bf16* __restrict__ kf) {
    int kt = blockIdx.x, kvh = blockIdx.y, b = blockIdx.z;
    int tid = threadIdx.x, lane = tid & 63, ks = tid >> 6;
    int lrow = lane & 15, quad = lane >> 4;
    const bf16* src = xkv + ((long)b * SEQ + kt * 64) * 1024 + kvh * HD;
    bf16* dst = kf + ((long)((b * NKVH + kvh) * 32 + kt)) * 8192;
#pragma unroll
    for (int nt = 0; nt < 4; ++nt) {
        bf16x8 v = *(const bf16x8*)(src + (long)(nt * 16 + lrow) * 1024 + ks * 32 + quad * 8);
        *(bf16x8*)(dst + ((nt * 4 + ks) * 64 + lane) * 8) = v;
    }
}

// Repack V^T into fragment-major tiles:
// vf[(b*4+kvh)*32 + kt][nt(4)][dt(8)][lane(64)][4] with
//   d = dt*16 + (lane&15), key = kt*64 + nt*16 + (lane>>4)*4 + j.
// This is the 16x16x16 A-operand order. Transpose via LDS.
__global__ __launch_bounds__(256) void repack_v(const bf16* __restrict__ xkv,
                                                bf16* __restrict__ vf) {
    __shared__ bf16 Vls[64][136];
    int kt = blockIdx.x, kvh = blockIdx.y, b = blockIdx.z;
    int tid = threadIdx.x;
    const bf16* src = xkv + ((long)b * SEQ + kt * 64) * 1024 + 512 + kvh * HD;
#pragma unroll
    for (int p = 0; p < 4; ++p) {
        int c = p * 256 + tid;
        int r = c >> 4, dc = (c & 15) * 8;
        *(uint4*)(&Vls[r][dc]) = *(const uint4*)(src + (long)r * 1024 + dc);
    }
    __syncthreads();
    int lane = tid & 63, w = tid >> 6, lrow = lane & 15, quad = lane >> 4;
    bf16* dst = vf + ((long)((b * NKVH + kvh) * 32 + kt)) * 8192;
#pragma unroll
    for (int nt = 0; nt < 4; ++nt)
#pragma unroll
        for (int dtl = 0; dtl < 2; ++dtl) {
            int dt = w * 2 + dtl;
            bf16x4 v = {Vls[nt * 16 + quad * 4 + 0][dt * 16 + lrow],
                        Vls[nt * 16 + quad * 4 + 1][dt * 16 + lrow],
                        Vls[nt * 16 + quad * 4 + 2][dt * 16 + lrow],
                        Vls[nt * 16 + quad * 4 + 3][dt * 16 + lrow]};
            *(bf16x4*)(dst + ((nt * 8 + dt) * 64 + lane) * 4) = v;
        }
}

// ---------------------------------------------------------------------------
// Flash attention, S^T register-P scheme + fragment-major K/V + paired q-tiles.
// Grid: (16 pairs, H, B), block 256 = 4 waves; block p runs q-tiles {31-p, p}.
// Staging: linear 16KB global_load_lds copies; all LDS reads lane-contiguous.
__global__ __launch_bounds__(256, 4) void attn_kernel(const bf16* __restrict__ Q,
                                                      const bf16* __restrict__ KF,
                                                      const bf16* __restrict__ VF,
                                                      bf16* __restrict__ O) {
    __shared__ bf16 Kf[4][4][512];   // [nt][ks][lane*8] — 16 KB
    __shared__ bf16 Vf[4][8][256];   // [nt][dt][lane*4] — 16 KB
    const int tid = threadIdx.x, wave = tid >> 6, lane = tid & 63;
    const int pr = blockIdx.x;
    const int h = blockIdx.y, b = blockIdx.z;
    const int kvh = h >> 2;
    const int lrow = lane & 15, quad = lane >> 4;
    const float scale = 0.08838834764831845f;  // 1/sqrt(128)

    const bf16* kfb = KF + ((long)(b * NKVH + kvh) * 32) * 8192;
    const bf16* vfb = VF + ((long)(b * NKVH + kvh) * 32) * 8192;
    bf16* kl = &Kf[0][0][0] + tid * 8;   // chunk c=tid (+256/turn): lane*16B in-wave
    bf16* vl = &Vf[0][0][0] + tid * 8;

#pragma unroll 1
    for (int t = 0; t < 2; ++t) {
        const int qt = t ? pr : (31 - pr);
        const int q0 = qt * 64;
        const int nkb = qt + 1;
        const int myq = q0 + wave * 16 + lrow;   // this lane's q row

        // Q B-fragments from global: B[n=q=lane&15][k=d=quad*8+j]
        const bf16* qrow = Q + ((long)(b * SEQ + myq)) * (NH * HD) + h * HD;
        bf16x8 bq[4];
#pragma unroll
        for (int ks = 0; ks < 4; ++ks)
            bq[ks] = *(const bf16x8*)(qrow + ks * 32 + quad * 8);

        float m_i = -__builtin_inff(), l_i = 0.f;
        f32x4 oT[8] = {};   // out^T: d = dt*16 + quad*4 + r, q = lane&15

        for (int kb = 0; kb < nkb; ++kb) {
            // async stage K-frag + V-frag tiles (linear 16 KB each)
            const bf16* kg = kfb + (long)kb * 8192 + tid * 8;
            const bf16* vg = vfb + (long)kb * 8192 + tid * 8;
#pragma unroll
            for (int p = 0; p < 4; ++p) {
                load_lds16(kg + p * 2048, kl + p * 2048);
                load_lds16(vg + p * 2048, vl + p * 2048);
            }
            __syncthreads();

            // S^T: key-tile nt covers keys kb*64+nt*16+quad*4+{0..3} for q=lrow
            f32x4 st[4];
            const bool diag = (kb == nkb - 1);
#pragma unroll
            for (int nt = 0; nt < 4; ++nt) {
                f32x4 acc = {};
#pragma unroll
                for (int ks = 0; ks < 4; ++ks) {
                    bf16x8 ak = *(const bf16x8*)(&Kf[nt][ks][lane * 8]);
                    acc = __builtin_amdgcn_mfma_f32_16x16x32_bf16(ak, bq[ks], acc, 0, 0, 0);
                }
                if (diag) {
                    int kp0 = kb * 64 + nt * 16 + quad * 4;
#pragma unroll
                    for (int r = 0; r < 4; ++r)
                        st[nt][r] = (kp0 + r <= myq) ? acc[r] * scale : -__builtin_inff();
                } else {
#pragma unroll
                    for (int r = 0; r < 4; ++r) st[nt][r] = acc[r] * scale;
                }
            }

            // per-lane online softmax (lane owns one q row; keys spread over quads)
            float mx = st[0][0];
#pragma unroll
            for (int nt = 0; nt < 4; ++nt)
#pragma unroll
                for (int r = 0; r < 4; ++r) mx = fmaxf(mx, st[nt][r]);
            mx = fmaxf(mx, __shfl_xor(mx, 16, 64));
            mx = fmaxf(mx, __shfl_xor(mx, 32, 64));
            float mnew = fmaxf(m_i, mx);
            float alpha = __expf(m_i - mnew);
            float rs = 0.f;
#pragma unroll
            for (int nt = 0; nt < 4; ++nt)
#pragma unroll
                for (int r = 0; r < 4; ++r) {
                    float p = __expf(st[nt][r] - mnew);
                    st[nt][r] = p;
                    rs += p;
                }
            rs += __shfl_xor(rs, 16, 64);
            rs += __shfl_xor(rs, 32, 64);
            l_i = l_i * alpha + rs;
            m_i = mnew;
#pragma unroll
            for (int dt = 0; dt < 8; ++dt)
#pragma unroll
                for (int r = 0; r < 4; ++r) oT[dt][r] *= alpha;

            // P fragments (16x16x16 B-operand): B[n=q=lane&15][k=key=quad*4+j]
            bf16x4 pf[4];
#pragma unroll
            for (int nt = 0; nt < 4; ++nt) {
                bf16x4 tt = {(bf16)st[nt][0], (bf16)st[nt][1],
                             (bf16)st[nt][2], (bf16)st[nt][3]};
                pf[nt] = tt;
            }

            // PV: out^T += V^T · P^T, key-steps of 16; A-frag at lane*8B
#pragma unroll
            for (int nt = 0; nt < 4; ++nt)
#pragma unroll
                for (int dt = 0; dt < 8; ++dt) {
                    bf16x4 av = *(const bf16x4*)(&Vf[nt][dt][lane * 4]);
                    oT[dt] = mfma_16x16x16(av, pf[nt], oT[dt]);
                }
            __syncthreads();  // protect Kf/Vf before next staging
        }

        // epilogue: lane writes q-row myq, d = dt*16+quad*4+{0..3} (8B stores)
        float inv_l = 1.0f / l_i;
        bf16* obase = O + ((long)(b * SEQ + myq)) * (NH * HD) + h * HD;
#pragma unroll
        for (int dt = 0; dt < 8; ++dt) {
            bf16x4 o = {(bf16)(oT[dt][0] * inv_l), (bf16)(oT[dt][1] * inv_l),
                        (bf16)(oT[dt][2] * inv_l), (bf16)(oT[dt][3] * inv_l)};
            *(bf16x4*)(obase + dt * 16 + quad * 4) = o;
        }
    }
}

// ---------------------------------------------------------------------------
extern "C" void kernel_launch(void* const* d_in, const int* in_sizes, int n_in,
                              void* d_out, int out_size, void* d_ws, size_t ws_size,
                              hipStream_t stream) {
    const float* q_stream  = (const float*)d_in[0];
    const float* kv_stream = (const float*)d_in[1];
    const float* wq  = (const float*)d_in[2];
    const float* wk  = (const float*)d_in[3];
    const float* wv  = (const float*)d_in[4];
    const float* wo  = (const float*)d_in[5];
    const float* qnw = (const float*)d_in[6];
    const float* knw = (const float*)d_in[7];
    float* out = (float*)d_out;

    // workspace (bf16 elems), total 30M elems = 60MB
    bf16* ws   = (bf16*)d_ws;
    bf16* sb   = ws;                        // 8M: stream buf, later attn out
    bf16* wqT  = ws + 8L * 1024 * 1024;     // 4M: wq^T, later wo^T
    bf16* wkvT = wqT + 4L * 1024 * 1024;    // 2M: [wk^T ; wv^T] = [1024][2048]
    bf16* xq   = wkvT + 2L * 1024 * 1024;   // 8M: [4096][2048]
    bf16* xkv  = xq + 8L * 1024 * 1024;     // 4M: [4096][1024] = [K | V]
    bf16* kf   = xkv + 4L * 1024 * 1024;    // 2M: K fragment-major
    bf16* vf   = kf + 2L * 1024 * 1024;     // 2M: V^T fragment-major

    dim3 tb(32, 8);
    cvt_f32_bf16<<<4096, 256, 0, stream>>>(q_stream, sb, 1048576);
    transpose2d<<<dim3(64, 64), tb, 0, stream>>>(wq, wqT, 2048, 2048);
    transpose2d<<<dim3(16, 64), tb, 0, stream>>>(wk, wkvT, 2048, 512);
    transpose2d<<<dim3(16, 64), tb, 0, stream>>>(wv, wkvT + 512L * 2048, 2048, 512);
    gemm_bt<bf16><<<dim3(16, 32), 256, 0, stream>>>(sb, wqT, xq, 4096, 2048, 2048);
    cvt_f32_bf16<<<4096, 256, 0, stream>>>(kv_stream, sb, 1048576);
    transpose2d<<<dim3(64, 64), tb, 0, stream>>>(wo, wqT, 2048, 2048);
    gemm_bt<bf16><<<dim3(8, 32), 256, 0, stream>>>(sb, wkvT, xkv, 4096, 1024, 2048);
    rmsnorm_head<<<(4096 * 16) / 4, 256, 0, stream>>>(xq, qnw, 4096 * 16, 4, 2048);
    rmsnorm_head<<<(4096 * 4) / 4, 256, 0, stream>>>(xkv, knw, 4096 * 4, 2, 1024);
    repack_k<<<dim3(32, 4, 2), 256, 0, stream>>>(xkv, kf);
    repack_v<<<dim3(32, 4, 2), 256, 0, stream>>>(xkv, vf);
    attn_kernel<<<dim3(16, 16, 2), 256, 0, stream>>>(xq, kf, vf, sb);
    gemm_bt<float><<<dim3(16, 32), 256, 0, stream>>>(sb, wqT, out, 4096, 2048, 2048);

    (void)in_sizes; (void)n_in; (void)out_size; (void)ws_size;
}